// Round 8
// baseline (581.265 us; speedup 1.0000x reference)
//
#include <hip/hip_runtime.h>
#include <hip/hip_bf16.h>

// Problem constants (RelateModel_652835029255)
#define NN 100000
#define EE 600000
#define DD 128
#define GG 256
#define CCL 16

typedef __attribute__((ext_vector_type(8))) short short8;
typedef __attribute__((ext_vector_type(4))) float f32x4;
typedef const __attribute__((address_space(1))) void* gas_t;
typedef __attribute__((address_space(3))) void* las_t;

__device__ __forceinline__ void async_ld16(const void* g, void* l) {
    __builtin_amdgcn_global_load_lds((gas_t)g, (las_t)l, 16, 0, 0);
}
__device__ __forceinline__ unsigned short f2bf(float x) {
    unsigned u = __float_as_uint(x);
    unsigned r = (u + 0x7FFFu + ((u >> 16) & 1u)) >> 16;
    return (unsigned short)r;
}
__device__ __forceinline__ float bf2f(unsigned short b) {
    return __uint_as_float(((unsigned)b) << 16);
}
__device__ __forceinline__ void unpack8(uint4 v, float* f) {
    f[0] = __uint_as_float(v.x << 16); f[1] = __uint_as_float(v.x & 0xFFFF0000u);
    f[2] = __uint_as_float(v.y << 16); f[3] = __uint_as_float(v.y & 0xFFFF0000u);
    f[4] = __uint_as_float(v.z << 16); f[5] = __uint_as_float(v.z & 0xFFFF0000u);
    f[6] = __uint_as_float(v.w << 16); f[7] = __uint_as_float(v.w & 0xFFFF0000u);
}

// ---------------- dtype sniff (f32 vs bf16 tensors) ----------------
__global__ __launch_bounds__(256) void sniff_kernel(const void* __restrict__ xraw, int* __restrict__ flag) {
    int t = threadIdx.x;
    const unsigned short* u = (const unsigned short*)xraw;
    int good = 0;
    #pragma unroll
    for (int i = 0; i < 4; i++) {
        unsigned short b = u[t * 4 + i];
        int e = (b >> 7) & 0xFF;
        if (e >= 107 && e <= 130) good++;
    }
    __shared__ int sg[256];
    sg[t] = good;
    __syncthreads();
    for (int s = 128; s > 0; s >>= 1) { if (t < s) sg[t] += sg[t + s]; __syncthreads(); }
    if (t == 0) flag[0] = (sg[0] >= 900) ? 1 : 0;   // 1 = data is bf16
}

__device__ __forceinline__ float loadf(const void* p, size_t i, int isbf) {
    if (isbf) return bf2f(((const unsigned short*)p)[i]);
    return ((const float*)p)[i];
}

__global__ __launch_bounds__(256) void convx_kernel(const void* __restrict__ xraw, const int* __restrict__ flag,
                                                    __hip_bfloat16* __restrict__ xc) {
    int isbf = flag[0];
    size_t i0 = ((size_t)blockIdx.x * 256 + threadIdx.x) * 8;
    if (i0 >= (size_t)NN * DD) return;
    if (isbf) {
        *(uint4*)(xc + i0) = *(const uint4*)((const __hip_bfloat16*)xraw + i0);
    } else {
        const float* xf = (const float*)xraw;
        unsigned short o[8];
        #pragma unroll
        for (int j = 0; j < 8; j++) o[j] = f2bf(xf[i0 + j]);
        *(uint4*)(xc + i0) = *(uint4*)o;
    }
}

// weights -> wt[mat][n][k] (transposed, bf16), mat = layer*5 + g (g0=root, g1..4=rel)
__global__ __launch_bounds__(256) void convw_kernel(const void* __restrict__ rel_raw, const void* __restrict__ root_raw,
                                                    const int* __restrict__ flag, __hip_bfloat16* __restrict__ wt) {
    int isbf = flag[0];
    int mat = blockIdx.x;
    int layer = mat / 5, g = mat % 5;
    size_t srcoff = (g == 0) ? (size_t)layer * 16384 : (size_t)(layer * 4 + (g - 1)) * 16384;
    const void* sraw = (g == 0) ? root_raw : rel_raw;
    __hip_bfloat16* dstp = wt + (size_t)mat * 16384;
    for (int idx = threadIdx.x; idx < 16384; idx += 256) {
        int k = idx >> 7, n = idx & 127;
        float v = loadf(sraw, srcoff + (size_t)k * 128 + n, isbf);
        dstp[n * 128 + k] = __float2bfloat16(v);
    }
}

// small params -> one f32 block; blocks 9,10 precompute BN gm/ga per layer.
__global__ __launch_bounds__(256) void convp_kernel(const void* bias, const void* bng, const void* bnb,
                                                    const void* bnm, const void* bnv, const void* w1,
                                                    const void* b1, const void* w2, const void* b2,
                                                    const int* __restrict__ flag, float* __restrict__ pf) {
    int isbf = flag[0];
    int b = blockIdx.x, t = threadIdx.x;
    if (b < 9) {
        const void* srcs[9] = {bias, bng, bnb, bnm, bnv, w1, b1, w2, b2};
        const int cnts[9] = {384, 256, 256, 256, 256, 8192, 64, 1024, 16};
        const int offs[9] = {0, 384, 640, 896, 1152, 1408, 9600, 9664, 10688};
        const void* s = srcs[b];
        int c = cnts[b], o = offs[b];
        for (int i = t; i < c; i += 256) pf[o + i] = loadf(s, i, isbf);
    } else {
        int bl = b - 9;
        if (t < 128) {
            float iva = rsqrtf(loadf(bnv, bl * 128 + t, isbf) + 1e-5f);
            float gm = loadf(bng, bl * 128 + t, isbf) * iva;
            float ga = loadf(bnb, bl * 128 + t, isbf) - loadf(bnm, bl * 128 + t, isbf) * gm;
            pf[11008 + bl * 256 + t] = gm;
            pf[11008 + bl * 256 + 128 + t] = ga;
        }
    }
}

// ---------------- CSR build: dst-sorted edge list w/ precomputed per-edge (offset, weight) ----------------
__global__ __launch_bounds__(256) void count4_kernel(const int* __restrict__ dst, const int* __restrict__ et,
                                                     int* __restrict__ cnt4) {
    int e = blockIdx.x * 256 + threadIdx.x;
    if (e < EE) atomicAdd(&cnt4[dst[e] * 4 + et[e]], 1);
}

__global__ __launch_bounds__(256) void allocn_kernel(const int* __restrict__ cnt4, int* __restrict__ counter,
                                                     int* __restrict__ startn, int* __restrict__ wptrn) {
    int n = blockIdx.x * 256 + threadIdx.x;
    int lane = threadIdx.x & 63;
    int c = 0;
    if (n < NN) {
        int4 cv = *(const int4*)(cnt4 + n * 4);
        c = cv.x + cv.y + cv.z + cv.w;
    }
    int v = c;
    #pragma unroll
    for (int d = 1; d < 64; d <<= 1) {
        int o = __shfl_up(v, d);
        if (lane >= d) v += o;
    }
    int base = 0;
    if (lane == 63) base = atomicAdd(counter, v);
    base = __shfl(base, 63);
    if (n < NN) {
        int s = base + v - c;
        startn[n] = s;
        wptrn[n] = s;
    }
}

// ewe[e] = (src*512 + rel*128, bits(1/cnt_rel(dst)))
__global__ __launch_bounds__(256) void filln_kernel(const int* __restrict__ src, const int* __restrict__ dst,
                                                    const int* __restrict__ et, const int* __restrict__ cnt4,
                                                    int* __restrict__ wptrn, int2* __restrict__ ewe) {
    int e = blockIdx.x * 256 + threadIdx.x;
    if (e < EE) {
        int d = dst[e], r = et[e];
        float w = 1.f / (float)cnt4[d * 4 + r];
        int pos = atomicAdd(&wptrn[d], 1);
        ewe[pos] = make_int2(src[e] * 512 + r * 128, __float_as_int(w));
    }
}

// ---------------- gemmY v2: Y = h @ [Wroot|W0..W3], one (tile,g) per block ----------------
// grid (1563, 5). Each block: stage its B_g (32 KB LDS), A direct->VGPR, 16 MFMA,
// swizzled-LDS repack, coalesced stores at block end (no barrier after stores).
__global__ __launch_bounds__(256) void gemmy_kernel(const __hip_bfloat16* __restrict__ h_in,
                                                    const __hip_bfloat16* __restrict__ wt5,  // [5][128 n][128 k]
                                                    __hip_bfloat16* __restrict__ Yroot,      // [N][128]
                                                    __hip_bfloat16* __restrict__ Yrel) {     // [N][512]
    __shared__ __align__(16) short Btile[16384];  // 32 KB
    __shared__ __align__(16) short Ctile[8192];   // 16 KB
    int t = threadIdx.x;
    int wave = t >> 6, lane = t & 63, quad = lane >> 4, r16 = lane & 15;
    int m0 = blockIdx.x * 64;
    int g = blockIdx.y;

    // stage B_g async
    const __hip_bfloat16* wg = wt5 + (size_t)g * 16384;
    #pragma unroll
    for (int j = 0; j < 8; j++) {
        int slot = j * 256 + t;
        int brow = slot >> 4, sp = slot & 15;
        async_ld16(wg + brow * 128 + (sp ^ (brow & 15)) * 8, &Btile[slot * 8]);
    }
    // A into registers
    int row = m0 + wave * 16 + r16;
    if (row > NN - 1) row = NN - 1;
    const __hip_bfloat16* ap = h_in + (size_t)row * 128;
    short8 a[4];
    #pragma unroll
    for (int kc = 0; kc < 4; kc++) a[kc] = *(const short8*)(ap + kc * 32 + quad * 8);

    __syncthreads();   // B_g staged (vmcnt drained by compiler before barrier)

    f32x4 acc[8];
    #pragma unroll
    for (int j = 0; j < 8; j++) acc[j] = (f32x4){0.f, 0.f, 0.f, 0.f};
    #pragma unroll
    for (int kc = 0; kc < 4; kc++) {
        int s = kc * 4 + quad;
        #pragma unroll
        for (int nt = 0; nt < 8; nt++) {
            int rb = nt * 16 + r16;
            short8 b = *(const short8*)&Btile[(rb * 16 + (s ^ (rb & 15))) * 8];
            acc[nt] = __builtin_amdgcn_mfma_f32_16x16x32_bf16(a[kc], b, acc[nt], 0, 0, 0);
        }
    }
    // repack C -> swizzled Ctile
    #pragma unroll
    for (int nt = 0; nt < 8; nt++) {
        int col = nt * 16 + r16;
        #pragma unroll
        for (int reg = 0; reg < 4; reg++) {
            int crow = wave * 16 + quad * 4 + reg;
            int sslot = (col >> 3) ^ (crow & 15);
            Ctile[crow * 128 + sslot * 8 + (col & 7)] = (short)f2bf(acc[nt][reg]);
        }
    }
    __syncthreads();
    // coalesced 16B stores; no barrier after (drain at kernel end)
    #pragma unroll
    for (int it = 0; it < 4; it++) {
        int u4 = it * 256 + t;
        int crow = u4 >> 4, seg = u4 & 15;
        int node = m0 + crow;
        if (node < NN) {
            int sslot = seg ^ (crow & 15);
            short8 cv = *(const short8*)&Ctile[crow * 128 + sslot * 8];
            __hip_bfloat16* dp = (g == 0) ? (Yroot + (size_t)node * 128 + seg * 8)
                                          : (Yrel + (size_t)node * 512 + (g - 1) * 128 + seg * 8);
            *(uint4*)dp = *(uint4*)&cv;
        }
    }
}

// ---------------- sagg: out[i] = Yroot[i] + sum_e w_e * Yrel[eidx_e]  (+bias,+res,+BN,+ELU) ----------
__global__ __launch_bounds__(256) void sagg_kernel(const __hip_bfloat16* __restrict__ Yrel,
                                                   const __hip_bfloat16* __restrict__ Yroot,
                                                   const int2* __restrict__ ewe,
                                                   const int* __restrict__ startn,
                                                   const int* __restrict__ wptrn,
                                                   const float* __restrict__ bias,
                                                   const float* __restrict__ gmp,
                                                   const float* __restrict__ gap,
                                                   const __hip_bfloat16* __restrict__ hres,
                                                   __hip_bfloat16* __restrict__ hout,
                                                   int do_bn) {
    int node = blockIdx.x * 16 + (threadIdx.x >> 4);
    int c16 = threadIdx.x & 15;
    int s = startn[node];
    int c = wptrn[node] - s;
    int col0 = c16 * 8;
    float a[8];
    unpack8(*(const uint4*)(Yroot + (size_t)node * 128 + col0), a);
    int i = 0;
    for (; i + 4 <= c; i += 4) {
        int2 e0 = ewe[s + i], e1 = ewe[s + i + 1], e2 = ewe[s + i + 2], e3 = ewe[s + i + 3];
        uint4 v0 = *(const uint4*)(Yrel + e0.x + col0);
        uint4 v1 = *(const uint4*)(Yrel + e1.x + col0);
        uint4 v2 = *(const uint4*)(Yrel + e2.x + col0);
        uint4 v3 = *(const uint4*)(Yrel + e3.x + col0);
        float w0 = __int_as_float(e0.y), w1 = __int_as_float(e1.y);
        float w2 = __int_as_float(e2.y), w3 = __int_as_float(e3.y);
        float f0[8], f1[8], f2[8], f3[8];
        unpack8(v0, f0); unpack8(v1, f1); unpack8(v2, f2); unpack8(v3, f3);
        #pragma unroll
        for (int j = 0; j < 8; j++)
            a[j] += w0 * f0[j] + w1 * f1[j] + w2 * f2[j] + w3 * f3[j];
    }
    for (; i < c; i++) {
        int2 e0 = ewe[s + i];
        uint4 v0 = *(const uint4*)(Yrel + e0.x + col0);
        float w0 = __int_as_float(e0.y);
        float f0[8];
        unpack8(v0, f0);
        #pragma unroll
        for (int j = 0; j < 8; j++) a[j] += w0 * f0[j];
    }
    if (hres) {
        float rf[8];
        unpack8(*(const uint4*)(hres + (size_t)node * 128 + col0), rf);
        #pragma unroll
        for (int j = 0; j < 8; j++) a[j] = a[j] + bias[col0 + j] + rf[j];
    } else {
        #pragma unroll
        for (int j = 0; j < 8; j++) a[j] = a[j] + bias[col0 + j];
    }
    if (do_bn) {
        #pragma unroll
        for (int j = 0; j < 8; j++) {
            float z = a[j] * gmp[col0 + j] + gap[col0 + j];
            a[j] = z > 0.f ? z : expm1f(z);
        }
    }
    unsigned short u[8];
    #pragma unroll
    for (int j = 0; j < 8; j++) u[j] = f2bf(a[j]);
    *(uint4*)(hout + (size_t)node * 128 + col0) = *(uint4*)u;
}

// ---------------- global mean pool (batch sorted) ----------------
__global__ __launch_bounds__(256) void pool_kernel(const __hip_bfloat16* __restrict__ h3,
                                                   const int* __restrict__ batch,
                                                   float* __restrict__ pooled) {
    int g = blockIdx.x, t = threadIdx.x;
    int rowpar = t >> 4, colg = t & 15;
    int lo = 0, hi = NN;
    while (lo < hi) { int mid = (lo + hi) >> 1; if (batch[mid] < g) lo = mid + 1; else hi = mid; }
    int s0 = lo;
    hi = NN;
    while (lo < hi) { int mid = (lo + hi) >> 1; if (batch[mid] < g + 1) lo = mid + 1; else hi = mid; }
    int s1 = lo;
    float a[8];
    #pragma unroll
    for (int j = 0; j < 8; j++) a[j] = 0.f;
    for (int n = s0 + rowpar; n < s1; n += 16) {
        float f[8];
        unpack8(*(const uint4*)(h3 + (size_t)n * 128 + colg * 8), f);
        #pragma unroll
        for (int j = 0; j < 8; j++) a[j] += f[j];
    }
    __shared__ float sd[16][128];
    #pragma unroll
    for (int j = 0; j < 8; j++) sd[rowpar][colg * 8 + j] = a[j];
    __syncthreads();
    if (t < 128) {
        float sum = 0.f;
        #pragma unroll
        for (int i = 0; i < 16; i++) sum += sd[i][t];
        int cgn = s1 - s0;
        pooled[g * 128 + t] = sum / (float)(cgn > 0 ? cgn : 1);
    }
}

// ---------------- classifier + log_softmax ----------------
__global__ __launch_bounds__(64) void cls_kernel(const float* __restrict__ pooled,
                                                 const float* __restrict__ pf,
                                                 const int* __restrict__ flag,
                                                 void* __restrict__ out) {
    int g = blockIdx.x, j = threadIdx.x;
    const float* w1 = pf + 1408;
    const float* b1 = pf + 9600;
    const float* w2 = pf + 9664;
    const float* b2 = pf + 10688;
    __shared__ float z[64];
    __shared__ float lg[16];
    const float* p = pooled + g * 128;
    float acc = b1[j];
    for (int d = 0; d < 128; d++) acc += p[d] * w1[d * 64 + j];
    acc = acc > 0.f ? acc : expm1f(acc);
    z[j] = acc;
    __syncthreads();
    if (j < CCL) {
        float l = b2[j];
        for (int k = 0; k < 64; k++) l += z[k] * w2[k * 16 + j];
        lg[j] = l;
    }
    __syncthreads();
    if (j < CCL) {
        float m = lg[0];
        for (int k = 1; k < CCL; k++) m = fmaxf(m, lg[k]);
        float s = 0.f;
        for (int k = 0; k < CCL; k++) s += expf(lg[k] - m);
        float val = lg[j] - m - logf(s);
        if (flag[0]) ((__hip_bfloat16*)out)[g * CCL + j] = __float2bfloat16(val);
        else         ((float*)out)[g * CCL + j] = val;
    }
}

extern "C" void kernel_launch(void* const* d_in, const int* in_sizes, int n_in,
                              void* d_out, int out_size, void* d_ws, size_t ws_size,
                              hipStream_t stream) {
    const void* x_raw    = d_in[0];
    const int* ei        = (const int*)d_in[1];
    const int* et        = (const int*)d_in[2];
    const int* batch     = (const int*)d_in[3];
    const void* rel_raw  = d_in[4];
    const void* root_raw = d_in[5];
    const int* srcp = ei;
    const int* dstp = ei + EE;

    char* ws = (char*)d_ws;
    size_t off = 0;
    auto take = [&](size_t bytes) { size_t r = off; off += (bytes + 1023) & ~(size_t)1023; return r; };
    __hip_bfloat16* Yrel  = (__hip_bfloat16*)(ws + take((size_t)NN * 512 * 2));   // 102.4 MB
    __hip_bfloat16* Yroot = (__hip_bfloat16*)(ws + take((size_t)NN * 128 * 2));   // 25.6 MB
    __hip_bfloat16* xc    = (__hip_bfloat16*)(ws + take((size_t)NN * 128 * 2));
    __hip_bfloat16* hA    = (__hip_bfloat16*)(ws + take((size_t)NN * 128 * 2));
    __hip_bfloat16* hB    = (__hip_bfloat16*)(ws + take((size_t)NN * 128 * 2));
    __hip_bfloat16* hC    = (__hip_bfloat16*)(ws + take((size_t)NN * 128 * 2));
    __hip_bfloat16* wt    = (__hip_bfloat16*)(ws + take((size_t)15 * 16384 * 2));
    float* pf             = (float*)(ws + take((size_t)11520 * 4));
    float* pooled         = (float*)(ws + take((size_t)GG * 128 * 4));
    int* cnt4             = (int*)(ws + take((size_t)NN * 16 + 8));
    int* counter          = cnt4 + NN * 4;
    int* flag             = cnt4 + NN * 4 + 1;
    int* startn           = (int*)(ws + take((size_t)NN * 4));
    int* wptrn            = (int*)(ws + take((size_t)NN * 4));
    int2* ewe             = (int2*)(ws + take((size_t)EE * 8));

    hipMemsetAsync(cnt4, 0, (size_t)NN * 16 + 4, stream);
    sniff_kernel<<<1, 256, 0, stream>>>(x_raw, flag);
    convx_kernel<<<(NN * DD / 8 + 255) / 256, 256, 0, stream>>>(x_raw, flag, xc);
    convw_kernel<<<15, 256, 0, stream>>>(rel_raw, root_raw, flag, wt);
    convp_kernel<<<11, 256, 0, stream>>>(d_in[6], d_in[7], d_in[8], d_in[9], d_in[10],
                                         d_in[11], d_in[12], d_in[13], d_in[14], flag, pf);
    count4_kernel<<<(EE + 255) / 256, 256, 0, stream>>>(dstp, et, cnt4);
    allocn_kernel<<<(NN + 255) / 256, 256, 0, stream>>>(cnt4, counter, startn, wptrn);
    filln_kernel<<<(EE + 255) / 256, 256, 0, stream>>>(srcp, dstp, et, cnt4, wptrn, ewe);

    const __hip_bfloat16* hin = xc;
    __hip_bfloat16* houts[3] = {hA, hB, hC};
    dim3 ggrid((NN + 63) / 64, 5);
    for (int l = 0; l < 3; l++) {
        int bl = l < 2 ? l : 1;
        gemmy_kernel<<<ggrid, 256, 0, stream>>>(hin, wt + (size_t)l * 5 * 16384, Yroot, Yrel);
        sagg_kernel<<<NN / 16, 256, 0, stream>>>(
            Yrel, Yroot, ewe, startn, wptrn, pf + l * 128,
            pf + 11008 + bl * 256, pf + 11008 + bl * 256 + 128,
            (l > 0) ? hin : (const __hip_bfloat16*)nullptr, houts[l], (l < 2) ? 1 : 0);
        hin = houts[l];
    }
    pool_kernel<<<GG, 256, 0, stream>>>(houts[2], batch, pooled);
    cls_kernel<<<GG, 64, 0, stream>>>(pooled, pf, flag, (void*)d_out);
}

// Round 9
// 577.306 us; speedup vs baseline: 1.0069x; 1.0069x over previous
//
#include <hip/hip_runtime.h>
#include <hip/hip_bf16.h>

// Problem constants (RelateModel_652835029255)
#define NN 100000
#define EE 600000
#define DD 128
#define GG 256
#define CCL 16

typedef __attribute__((ext_vector_type(8))) short short8;
typedef __attribute__((ext_vector_type(4))) float f32x4;
typedef const __attribute__((address_space(1))) void* gas_t;
typedef __attribute__((address_space(3))) void* las_t;

__device__ __forceinline__ void async_ld16(const void* g, void* l) {
    __builtin_amdgcn_global_load_lds((gas_t)g, (las_t)l, 16, 0, 0);
}
__device__ __forceinline__ unsigned short f2bf(float x) {
    unsigned u = __float_as_uint(x);
    unsigned r = (u + 0x7FFFu + ((u >> 16) & 1u)) >> 16;
    return (unsigned short)r;
}
__device__ __forceinline__ float bf2f(unsigned short b) {
    return __uint_as_float(((unsigned)b) << 16);
}
__device__ __forceinline__ void unpack8(uint4 v, float* f) {
    f[0] = __uint_as_float(v.x << 16); f[1] = __uint_as_float(v.x & 0xFFFF0000u);
    f[2] = __uint_as_float(v.y << 16); f[3] = __uint_as_float(v.y & 0xFFFF0000u);
    f[4] = __uint_as_float(v.z << 16); f[5] = __uint_as_float(v.z & 0xFFFF0000u);
    f[6] = __uint_as_float(v.w << 16); f[7] = __uint_as_float(v.w & 0xFFFF0000u);
}

// ---------------- dtype sniff (f32 vs bf16 tensors) ----------------
__global__ __launch_bounds__(256) void sniff_kernel(const void* __restrict__ xraw, int* __restrict__ flag) {
    int t = threadIdx.x;
    const unsigned short* u = (const unsigned short*)xraw;
    int good = 0;
    #pragma unroll
    for (int i = 0; i < 4; i++) {
        unsigned short b = u[t * 4 + i];
        int e = (b >> 7) & 0xFF;
        if (e >= 107 && e <= 130) good++;
    }
    __shared__ int sg[256];
    sg[t] = good;
    __syncthreads();
    for (int s = 128; s > 0; s >>= 1) { if (t < s) sg[t] += sg[t + s]; __syncthreads(); }
    if (t == 0) flag[0] = (sg[0] >= 900) ? 1 : 0;   // 1 = data is bf16
}

__device__ __forceinline__ float loadf(const void* p, size_t i, int isbf) {
    if (isbf) return bf2f(((const unsigned short*)p)[i]);
    return ((const float*)p)[i];
}

__global__ __launch_bounds__(256) void convx_kernel(const void* __restrict__ xraw, const int* __restrict__ flag,
                                                    __hip_bfloat16* __restrict__ xc) {
    int isbf = flag[0];
    size_t i0 = ((size_t)blockIdx.x * 256 + threadIdx.x) * 8;
    if (i0 >= (size_t)NN * DD) return;
    if (isbf) {
        *(uint4*)(xc + i0) = *(const uint4*)((const __hip_bfloat16*)xraw + i0);
    } else {
        const float* xf = (const float*)xraw;
        unsigned short o[8];
        #pragma unroll
        for (int j = 0; j < 8; j++) o[j] = f2bf(xf[i0 + j]);
        *(uint4*)(xc + i0) = *(uint4*)o;
    }
}

// weights -> wt[mat][n][k] (transposed, bf16), mat = layer*5 + g (g0=root, g1..4=rel)
__global__ __launch_bounds__(256) void convw_kernel(const void* __restrict__ rel_raw, const void* __restrict__ root_raw,
                                                    const int* __restrict__ flag, __hip_bfloat16* __restrict__ wt) {
    int isbf = flag[0];
    int mat = blockIdx.x;
    int layer = mat / 5, g = mat % 5;
    size_t srcoff = (g == 0) ? (size_t)layer * 16384 : (size_t)(layer * 4 + (g - 1)) * 16384;
    const void* sraw = (g == 0) ? root_raw : rel_raw;
    __hip_bfloat16* dstp = wt + (size_t)mat * 16384;
    for (int idx = threadIdx.x; idx < 16384; idx += 256) {
        int k = idx >> 7, n = idx & 127;
        float v = loadf(sraw, srcoff + (size_t)k * 128 + n, isbf);
        dstp[n * 128 + k] = __float2bfloat16(v);
    }
}

// small params -> one f32 block; blocks 9,10 precompute BN gm/ga per layer.
__global__ __launch_bounds__(256) void convp_kernel(const void* bias, const void* bng, const void* bnb,
                                                    const void* bnm, const void* bnv, const void* w1,
                                                    const void* b1, const void* w2, const void* b2,
                                                    const int* __restrict__ flag, float* __restrict__ pf) {
    int isbf = flag[0];
    int b = blockIdx.x, t = threadIdx.x;
    if (b < 9) {
        const void* srcs[9] = {bias, bng, bnb, bnm, bnv, w1, b1, w2, b2};
        const int cnts[9] = {384, 256, 256, 256, 256, 8192, 64, 1024, 16};
        const int offs[9] = {0, 384, 640, 896, 1152, 1408, 9600, 9664, 10688};
        const void* s = srcs[b];
        int c = cnts[b], o = offs[b];
        for (int i = t; i < c; i += 256) pf[o + i] = loadf(s, i, isbf);
    } else {
        int bl = b - 9;
        if (t < 128) {
            float iva = rsqrtf(loadf(bnv, bl * 128 + t, isbf) + 1e-5f);
            float gm = loadf(bng, bl * 128 + t, isbf) * iva;
            float ga = loadf(bnb, bl * 128 + t, isbf) - loadf(bnm, bl * 128 + t, isbf) * gm;
            pf[11008 + bl * 256 + t] = gm;
            pf[11008 + bl * 256 + 128 + t] = ga;
        }
    }
}

// ---------------- CSR build: dst-sorted edge list w/ precomputed per-edge (offset, weight) ----------------
__global__ __launch_bounds__(256) void count4_kernel(const int* __restrict__ dst, const int* __restrict__ et,
                                                     int* __restrict__ cnt4) {
    int e = blockIdx.x * 256 + threadIdx.x;
    if (e < EE) atomicAdd(&cnt4[dst[e] * 4 + et[e]], 1);
}

__global__ __launch_bounds__(256) void allocn_kernel(const int* __restrict__ cnt4, int* __restrict__ counter,
                                                     int* __restrict__ startn, int* __restrict__ wptrn) {
    int n = blockIdx.x * 256 + threadIdx.x;
    int lane = threadIdx.x & 63;
    int c = 0;
    if (n < NN) {
        int4 cv = *(const int4*)(cnt4 + n * 4);
        c = cv.x + cv.y + cv.z + cv.w;
    }
    int v = c;
    #pragma unroll
    for (int d = 1; d < 64; d <<= 1) {
        int o = __shfl_up(v, d);
        if (lane >= d) v += o;
    }
    int base = 0;
    if (lane == 63) base = atomicAdd(counter, v);
    base = __shfl(base, 63);
    if (n < NN) {
        int s = base + v - c;
        startn[n] = s;
        wptrn[n] = s;
    }
}

// ewe[e] = (src*512 + rel*128, bits(1/cnt_rel(dst)))
__global__ __launch_bounds__(256) void filln_kernel(const int* __restrict__ src, const int* __restrict__ dst,
                                                    const int* __restrict__ et, const int* __restrict__ cnt4,
                                                    int* __restrict__ wptrn, int2* __restrict__ ewe) {
    int e = blockIdx.x * 256 + threadIdx.x;
    if (e < EE) {
        int d = dst[e], r = et[e];
        float w = 1.f / (float)cnt4[d * 4 + r];
        int pos = atomicAdd(&wptrn[d], 1);
        ewe[pos] = make_int2(src[e] * 512 + r * 128, __float_as_int(w));
    }
}

// ---------------- gemmY v3: Y = h @ [Wroot|W0..W3], one (tile,g) per block, BM=128 ----------------
// grid (782, 5). LDS overlay: 32 KB B tile reused as 128x128 bf16 C tile. No store before a barrier.
__global__ __launch_bounds__(256) void gemmy_kernel(const __hip_bfloat16* __restrict__ h_in,
                                                    const __hip_bfloat16* __restrict__ wt5,  // [5][128 n][128 k]
                                                    __hip_bfloat16* __restrict__ Yroot,      // [N][128]
                                                    __hip_bfloat16* __restrict__ Yrel) {     // [N][512]
    __shared__ __align__(16) short lds[16384];   // 32 KB: Btile, then Ctile
    int t = threadIdx.x;
    int wave = t >> 6, lane = t & 63, quad = lane >> 4, r16 = lane & 15;
    int m0 = blockIdx.x * 128;
    int g = blockIdx.y;

    // stage B_g async (XOR-swizzled)
    const __hip_bfloat16* wg = wt5 + (size_t)g * 16384;
    #pragma unroll
    for (int j = 0; j < 8; j++) {
        int slot = j * 256 + t;
        int brow = slot >> 4, sp = slot & 15;
        async_ld16(wg + brow * 128 + (sp ^ (brow & 15)) * 8, &lds[slot * 8]);
    }
    // A into registers: wave handles rows m0+wave*32 .. +31 (two 16-row MFMA tiles)
    int r0 = m0 + wave * 32 + r16;      if (r0 > NN - 1) r0 = NN - 1;
    int r1 = m0 + wave * 32 + 16 + r16; if (r1 > NN - 1) r1 = NN - 1;
    const __hip_bfloat16* ap0 = h_in + (size_t)r0 * 128;
    const __hip_bfloat16* ap1 = h_in + (size_t)r1 * 128;
    short8 a0[4], a1[4];
    #pragma unroll
    for (int kc = 0; kc < 4; kc++) {
        a0[kc] = *(const short8*)(ap0 + kc * 32 + quad * 8);
        a1[kc] = *(const short8*)(ap1 + kc * 32 + quad * 8);
    }
    __syncthreads();   // B staged (vmcnt drained), A loads also complete

    f32x4 acc[2][8];
    #pragma unroll
    for (int i = 0; i < 2; i++)
        #pragma unroll
        for (int j = 0; j < 8; j++) acc[i][j] = (f32x4){0.f, 0.f, 0.f, 0.f};
    #pragma unroll
    for (int kc = 0; kc < 4; kc++) {
        int s = kc * 4 + quad;
        #pragma unroll
        for (int nt = 0; nt < 8; nt++) {
            int rb = nt * 16 + r16;
            short8 b = *(const short8*)&lds[(rb * 16 + (s ^ (rb & 15))) * 8];
            acc[0][nt] = __builtin_amdgcn_mfma_f32_16x16x32_bf16(a0[kc], b, acc[0][nt], 0, 0, 0);
            acc[1][nt] = __builtin_amdgcn_mfma_f32_16x16x32_bf16(a1[kc], b, acc[1][nt], 0, 0, 0);
        }
    }
    __syncthreads();   // all Btile reads done -> safe to overwrite as Ctile

    // repack C -> swizzled Ctile (same 32 KB)
    #pragma unroll
    for (int nt = 0; nt < 8; nt++) {
        int col = nt * 16 + r16;
        #pragma unroll
        for (int mt = 0; mt < 2; mt++) {
            #pragma unroll
            for (int reg = 0; reg < 4; reg++) {
                int crow = wave * 32 + mt * 16 + quad * 4 + reg;
                int sslot = (col >> 3) ^ (crow & 15);
                lds[crow * 128 + sslot * 8 + (col & 7)] = (short)f2bf(acc[mt][nt][reg]);
            }
        }
    }
    __syncthreads();   // Ctile complete

    // coalesced 16B stores; stores drain at kernel end (no barrier after)
    #pragma unroll
    for (int it = 0; it < 8; it++) {
        int u4 = it * 256 + t;
        int crow = u4 >> 4, seg = u4 & 15;
        int node = m0 + crow;
        if (node < NN) {
            int sslot = seg ^ (crow & 15);
            short8 cv = *(const short8*)&lds[crow * 128 + sslot * 8];
            __hip_bfloat16* dp = (g == 0) ? (Yroot + (size_t)node * 128 + seg * 8)
                                          : (Yrel + (size_t)node * 512 + (g - 1) * 128 + seg * 8);
            *(uint4*)dp = *(uint4*)&cv;
        }
    }
}

// ---------------- sagg v2: out[i] = Yroot[i] + sum_e w_e * Yrel[eidx_e]  (+bias,+res,+BN,+ELU) --------
// 16-lane group per node; 8-wide / 4-wide / scalar unrolled independent gathers.
__global__ __launch_bounds__(256) void sagg_kernel(const __hip_bfloat16* __restrict__ Yrel,
                                                   const __hip_bfloat16* __restrict__ Yroot,
                                                   const int2* __restrict__ ewe,
                                                   const int* __restrict__ startn,
                                                   const int* __restrict__ wptrn,
                                                   const float* __restrict__ bias,
                                                   const float* __restrict__ gmp,
                                                   const float* __restrict__ gap,
                                                   const __hip_bfloat16* __restrict__ hres,
                                                   __hip_bfloat16* __restrict__ hout,
                                                   int do_bn) {
    int node = blockIdx.x * 16 + (threadIdx.x >> 4);
    int c16 = threadIdx.x & 15;
    int s = startn[node];
    int c = wptrn[node] - s;
    int col0 = c16 * 8;
    float a[8];
    unpack8(*(const uint4*)(Yroot + (size_t)node * 128 + col0), a);
    int i = 0;
    for (; i + 8 <= c; i += 8) {
        int2 ee[8];
        uint4 vv[8];
        #pragma unroll
        for (int q = 0; q < 8; q++) ee[q] = ewe[s + i + q];
        #pragma unroll
        for (int q = 0; q < 8; q++) vv[q] = *(const uint4*)(Yrel + ee[q].x + col0);
        #pragma unroll
        for (int q = 0; q < 8; q++) {
            float w = __int_as_float(ee[q].y);
            float f[8];
            unpack8(vv[q], f);
            #pragma unroll
            for (int j = 0; j < 8; j++) a[j] += w * f[j];
        }
    }
    for (; i + 4 <= c; i += 4) {
        int2 ee[4];
        uint4 vv[4];
        #pragma unroll
        for (int q = 0; q < 4; q++) ee[q] = ewe[s + i + q];
        #pragma unroll
        for (int q = 0; q < 4; q++) vv[q] = *(const uint4*)(Yrel + ee[q].x + col0);
        #pragma unroll
        for (int q = 0; q < 4; q++) {
            float w = __int_as_float(ee[q].y);
            float f[8];
            unpack8(vv[q], f);
            #pragma unroll
            for (int j = 0; j < 8; j++) a[j] += w * f[j];
        }
    }
    for (; i < c; i++) {
        int2 e0 = ewe[s + i];
        uint4 v0 = *(const uint4*)(Yrel + e0.x + col0);
        float w0 = __int_as_float(e0.y);
        float f0[8];
        unpack8(v0, f0);
        #pragma unroll
        for (int j = 0; j < 8; j++) a[j] += w0 * f0[j];
    }
    if (hres) {
        float rf[8];
        unpack8(*(const uint4*)(hres + (size_t)node * 128 + col0), rf);
        #pragma unroll
        for (int j = 0; j < 8; j++) a[j] = a[j] + bias[col0 + j] + rf[j];
    } else {
        #pragma unroll
        for (int j = 0; j < 8; j++) a[j] = a[j] + bias[col0 + j];
    }
    if (do_bn) {
        #pragma unroll
        for (int j = 0; j < 8; j++) {
            float z = a[j] * gmp[col0 + j] + gap[col0 + j];
            a[j] = z > 0.f ? z : expm1f(z);
        }
    }
    unsigned short u[8];
    #pragma unroll
    for (int j = 0; j < 8; j++) u[j] = f2bf(a[j]);
    *(uint4*)(hout + (size_t)node * 128 + col0) = *(uint4*)u;
}

// ---------------- global mean pool (batch sorted) ----------------
__global__ __launch_bounds__(256) void pool_kernel(const __hip_bfloat16* __restrict__ h3,
                                                   const int* __restrict__ batch,
                                                   float* __restrict__ pooled) {
    int g = blockIdx.x, t = threadIdx.x;
    int rowpar = t >> 4, colg = t & 15;
    int lo = 0, hi = NN;
    while (lo < hi) { int mid = (lo + hi) >> 1; if (batch[mid] < g) lo = mid + 1; else hi = mid; }
    int s0 = lo;
    hi = NN;
    while (lo < hi) { int mid = (lo + hi) >> 1; if (batch[mid] < g + 1) lo = mid + 1; else hi = mid; }
    int s1 = lo;
    float a[8];
    #pragma unroll
    for (int j = 0; j < 8; j++) a[j] = 0.f;
    for (int n = s0 + rowpar; n < s1; n += 16) {
        float f[8];
        unpack8(*(const uint4*)(h3 + (size_t)n * 128 + colg * 8), f);
        #pragma unroll
        for (int j = 0; j < 8; j++) a[j] += f[j];
    }
    __shared__ float sd[16][128];
    #pragma unroll
    for (int j = 0; j < 8; j++) sd[rowpar][colg * 8 + j] = a[j];
    __syncthreads();
    if (t < 128) {
        float sum = 0.f;
        #pragma unroll
        for (int i = 0; i < 16; i++) sum += sd[i][t];
        int cgn = s1 - s0;
        pooled[g * 128 + t] = sum / (float)(cgn > 0 ? cgn : 1);
    }
}

// ---------------- classifier + log_softmax ----------------
__global__ __launch_bounds__(64) void cls_kernel(const float* __restrict__ pooled,
                                                 const float* __restrict__ pf,
                                                 const int* __restrict__ flag,
                                                 void* __restrict__ out) {
    int g = blockIdx.x, j = threadIdx.x;
    const float* w1 = pf + 1408;
    const float* b1 = pf + 9600;
    const float* w2 = pf + 9664;
    const float* b2 = pf + 10688;
    __shared__ float z[64];
    __shared__ float lg[16];
    const float* p = pooled + g * 128;
    float acc = b1[j];
    for (int d = 0; d < 128; d++) acc += p[d] * w1[d * 64 + j];
    acc = acc > 0.f ? acc : expm1f(acc);
    z[j] = acc;
    __syncthreads();
    if (j < CCL) {
        float l = b2[j];
        for (int k = 0; k < 64; k++) l += z[k] * w2[k * 16 + j];
        lg[j] = l;
    }
    __syncthreads();
    if (j < CCL) {
        float m = lg[0];
        for (int k = 1; k < CCL; k++) m = fmaxf(m, lg[k]);
        float s = 0.f;
        for (int k = 0; k < CCL; k++) s += expf(lg[k] - m);
        float val = lg[j] - m - logf(s);
        if (flag[0]) ((__hip_bfloat16*)out)[g * CCL + j] = __float2bfloat16(val);
        else         ((float*)out)[g * CCL + j] = val;
    }
}

extern "C" void kernel_launch(void* const* d_in, const int* in_sizes, int n_in,
                              void* d_out, int out_size, void* d_ws, size_t ws_size,
                              hipStream_t stream) {
    const void* x_raw    = d_in[0];
    const int* ei        = (const int*)d_in[1];
    const int* et        = (const int*)d_in[2];
    const int* batch     = (const int*)d_in[3];
    const void* rel_raw  = d_in[4];
    const void* root_raw = d_in[5];
    const int* srcp = ei;
    const int* dstp = ei + EE;

    char* ws = (char*)d_ws;
    size_t off = 0;
    auto take = [&](size_t bytes) { size_t r = off; off += (bytes + 1023) & ~(size_t)1023; return r; };
    __hip_bfloat16* Yrel  = (__hip_bfloat16*)(ws + take((size_t)NN * 512 * 2));   // 102.4 MB
    __hip_bfloat16* Yroot = (__hip_bfloat16*)(ws + take((size_t)NN * 128 * 2));   // 25.6 MB
    __hip_bfloat16* xc    = (__hip_bfloat16*)(ws + take((size_t)NN * 128 * 2));
    __hip_bfloat16* hA    = (__hip_bfloat16*)(ws + take((size_t)NN * 128 * 2));
    __hip_bfloat16* hB    = (__hip_bfloat16*)(ws + take((size_t)NN * 128 * 2));
    __hip_bfloat16* hC    = (__hip_bfloat16*)(ws + take((size_t)NN * 128 * 2));
    __hip_bfloat16* wt    = (__hip_bfloat16*)(ws + take((size_t)15 * 16384 * 2));
    float* pf             = (float*)(ws + take((size_t)11520 * 4));
    float* pooled         = (float*)(ws + take((size_t)GG * 128 * 4));
    int* cnt4             = (int*)(ws + take((size_t)NN * 16 + 8));
    int* counter          = cnt4 + NN * 4;
    int* flag             = cnt4 + NN * 4 + 1;
    int* startn           = (int*)(ws + take((size_t)NN * 4));
    int* wptrn            = (int*)(ws + take((size_t)NN * 4));
    int2* ewe             = (int2*)(ws + take((size_t)EE * 8));

    hipMemsetAsync(cnt4, 0, (size_t)NN * 16 + 4, stream);
    sniff_kernel<<<1, 256, 0, stream>>>(x_raw, flag);
    convx_kernel<<<(NN * DD / 8 + 255) / 256, 256, 0, stream>>>(x_raw, flag, xc);
    convw_kernel<<<15, 256, 0, stream>>>(rel_raw, root_raw, flag, wt);
    convp_kernel<<<11, 256, 0, stream>>>(d_in[6], d_in[7], d_in[8], d_in[9], d_in[10],
                                         d_in[11], d_in[12], d_in[13], d_in[14], flag, pf);
    count4_kernel<<<(EE + 255) / 256, 256, 0, stream>>>(dstp, et, cnt4);
    allocn_kernel<<<(NN + 255) / 256, 256, 0, stream>>>(cnt4, counter, startn, wptrn);
    filln_kernel<<<(EE + 255) / 256, 256, 0, stream>>>(srcp, dstp, et, cnt4, wptrn, ewe);

    const __hip_bfloat16* hin = xc;
    __hip_bfloat16* houts[3] = {hA, hB, hC};
    dim3 ggrid((NN + 127) / 128, 5);
    for (int l = 0; l < 3; l++) {
        int bl = l < 2 ? l : 1;
        gemmy_kernel<<<ggrid, 256, 0, stream>>>(hin, wt + (size_t)l * 5 * 16384, Yroot, Yrel);
        sagg_kernel<<<NN / 16, 256, 0, stream>>>(
            Yrel, Yroot, ewe, startn, wptrn, pf + l * 128,
            pf + 11008 + bl * 256, pf + 11008 + bl * 256 + 128,
            (l > 0) ? hin : (const __hip_bfloat16*)nullptr, houts[l], (l < 2) ? 1 : 0);
        hin = houts[l];
    }
    pool_kernel<<<GG, 256, 0, stream>>>(houts[2], batch, pooled);
    cls_kernel<<<GG, 64, 0, stream>>>(pooled, pf, flag, (void*)d_out);
}